// Round 9
// baseline (171.827 us; speedup 1.0000x reference)
//
#include <hip/hip_runtime.h>
#include <hip/hip_bf16.h>
#include <math.h>

typedef __attribute__((ext_vector_type(8))) short bf16x8;
typedef __attribute__((ext_vector_type(4))) float f32x4;
typedef __attribute__((ext_vector_type(16))) float f32x16;
typedef unsigned short u16;
typedef unsigned int u32;

#define BB 2
#define NN 6
#define MM 625
#define HWSZ 1680
#define NQ 3750
#define NK 10080
#define HEADS 4
#define EPSV 1e-5f
#define KC 9
#define KCHUNK 1120
#define NIT 35               // KCHUNK/32 exact, no fake keys
#define NQT32 118            // ceil(3750/32)
#define QPRESCALE 0.25503489f   // (1/sqrt(32)) * log2(e)

// ---- workspace offsets (floats) ----
#define OFF_QH   0          // bf16 960000  u16 -> 480000 fl  (row-major [row][128])
#define OFF_KH   480000     // bf16 2580480 u16 -> 1290240 fl (head-major [b][h][key][32])
#define OFF_VH   1770240    // bf16 2580480 u16                (transposed [b][h][dh][key])
#define OFF_PACC 3060480    // bf16 2*4*9*3750*32 u16 -> 4320000 fl
#define OFF_PL   7380480    // 270000 fl
#define OFF_ZN   8130480    // bf16 960000 u16 -> 480000 fl
#define OFF_HMID 8610480    // bf16 1920000 u16 -> 960000 fl
#define OFF_WTB  9570480    // 131072 u16 -> 65536 fl ; end 9636016

// u16 offsets inside WTB
#define WT_Q    0
#define WT_K    16384
#define WT_V    32768
#define WT_PROJ 49152
#define WT_W1   65536      // [256][128]
#define WT_W2   98304      // [128][256]

#define VEXP(d, s_) asm("v_exp_f32 %0, %1\n\ts_nop 0" : "=v"(d) : "v"(s_))
#define CVTPK(d, a, b) asm("v_cvt_pk_bf16_f32 %0, %1, %2" : "=v"(d) : "v"(a), "v"(b))

__device__ inline u16 f2bf(float f) {
    __hip_bfloat16 h = __float2bfloat16(f);
    return *reinterpret_cast<u16*>(&h);
}
__device__ inline float bf2f(u16 u) {
    u32 x = ((u32)u) << 16;
    return *reinterpret_cast<float*>(&x);
}
__device__ inline bf16x8 mk_frag(u32 a, u32 b, u32 c, u32 d) {
    union { u32 u[4]; bf16x8 v; } x;
    x.u[0] = a; x.u[1] = b; x.u[2] = c; x.u[3] = d;
    return x.v;
}

// weights -> bf16 transposed
__global__ void __launch_bounds__(256) k_prep(
        const float* __restrict__ wq, const float* __restrict__ wk,
        const float* __restrict__ wv, const float* __restrict__ pw,
        const float* __restrict__ w1, const float* __restrict__ w2,
        u16* __restrict__ wtb) {
    int idx = blockIdx.x * 256 + threadIdx.x;   // 131072 exact
    float v;
    if (idx < 65536) {
        const float* src = (idx < 16384) ? wq : (idx < 32768) ? wk
                         : (idx < 49152) ? wv : pw;
        int r = idx & 16383;
        int c = r >> 7, kk = r & 127;
        v = src[kk * 128 + c];
    } else if (idx < 98304) {
        int r = idx - 65536;
        int c = r >> 7, kk = r & 127;
        v = w1[kk * 256 + c];
    } else {
        int r = idx - 98304;
        int c = r >> 8, kk = r & 255;
        v = w2[kk * 128 + c];
    }
    wtb[idx] = f2bf(v);
}

// LN (over 128 ch, channel-strided input) + MFMA 128x128 projection -> bf16.
// mode 0: row-major [row][128] ; mode 1: head-major [b][h][key][32] ;
// mode 2: transposed head-major [b][h][dh][key]  (for V^T)
__global__ void __launch_bounds__(128) k_lnproj(const float* __restrict__ x, int S, int rows,
        const float* __restrict__ gam, const float* __restrict__ bet,
        const u16* __restrict__ wt, const float* __restrict__ bias,
        float oscale, int mode, int nk, u16* __restrict__ outp) {
    __shared__ float xs[32][132];
    __shared__ float smu[32], srs[32];
    const int t = threadIdx.x;
    const int g0 = blockIdx.x * 32;
    {   // transposed coalesced load
        const int sl = t & 31, du = t >> 5;
        const int grow = g0 + sl;
        const bool vload = grow < rows;
        const int bn = grow / S, ss = grow % S;
        const float* xbase = x + (size_t)bn * 128 * S + ss;
        for (int it = 0; it < 32; ++it) {
            int dd = it * 4 + du;
            xs[sl][dd] = vload ? xbase[(size_t)dd * S] : 0.f;
        }
    }
    __syncthreads();
    {   // stats, 4 threads/row
        const int r = t >> 2, p = t & 3;
        float sum = 0.f, sq = 0.f;
        for (int j = 0; j < 32; ++j) {
            float v = xs[r][p + 4 * j];
            sum += v; sq += v * v;
        }
        sum += __shfl_xor(sum, 1); sq += __shfl_xor(sq, 1);
        sum += __shfl_xor(sum, 2); sq += __shfl_xor(sq, 2);
        if (p == 0) {
            float mu = sum * (1.f / 128.f);
            float var = sq * (1.f / 128.f) - mu * mu;
            smu[r] = mu;
            srs[r] = rsqrtf(var + EPSV);
        }
    }
    __syncthreads();
    {   // normalize in LDS
        const float gv = gam[t], bv = bet[t];
        for (int rr = 0; rr < 32; ++rr)
            xs[rr][t] = (xs[rr][t] - smu[rr]) * srs[rr] * gv + bv;
    }
    __syncthreads();
    // MFMA GEMM: wave wid covers cols wid*64..+63
    const int lane = t & 63, wid = t >> 6;
    const int rl = lane & 31, hi = lane >> 5;
    bf16x8 afrag[8];
    #pragma unroll
    for (int ks = 0; ks < 8; ++ks) {
        float4 u = *(const float4*)&xs[rl][ks * 16 + hi * 8];
        float4 w = *(const float4*)&xs[rl][ks * 16 + hi * 8 + 4];
        u32 d0, d1, d2, d3;
        CVTPK(d0, u.x, u.y);
        CVTPK(d1, u.z, u.w);
        CVTPK(d2, w.x, w.y);
        CVTPK(d3, w.z, w.w);
        afrag[ks] = mk_frag(d0, d1, d2, d3);
    }
    u16* au = (u16*)&xs[0][0];      // alias, used only in mode 2
    if (mode == 2) __syncthreads(); // all waves done reading xs
    #pragma unroll
    for (int tile = 0; tile < 2; ++tile) {
        const int c = wid * 64 + tile * 32 + rl;
        f32x16 acc;
        #pragma unroll
        for (int i = 0; i < 16; ++i) acc[i] = 0.f;
        #pragma unroll
        for (int ks = 0; ks < 8; ++ks) {
            bf16x8 bfrag = *(const bf16x8*)(wt + (size_t)c * 128 + ks * 16 + hi * 8);
            acc = __builtin_amdgcn_mfma_f32_32x32x16_bf16(afrag[ks], bfrag, acc, 0, 0, 0);
        }
        const float bb = bias[c];
        #pragma unroll
        for (int reg = 0; reg < 16; ++reg) {
            int row = (reg & 3) + 8 * (reg >> 2) + 4 * hi;
            int grow = g0 + row;
            u16 val = f2bf((acc[reg] + bb) * oscale);
            if (mode == 2) {
                au[row * 132 + c] = val;
            } else if (mode == 1) {
                if (grow < rows) {
                    int b = (grow >= nk) ? 1 : 0;
                    int key = grow - b * nk;
                    outp[(((size_t)b * HEADS + (c >> 5)) * nk + key) * 32 + (c & 31)] = val;
                }
            } else {
                if (grow < rows) outp[(size_t)grow * 128 + c] = val;
            }
        }
    }
    if (mode == 2) {
        __syncthreads();
        const int b = (g0 >= nk) ? 1 : 0;
        const int key0 = g0 - b * nk;
        // coalesced transposed store: lanes sweep key
        for (int it = 0; it < 32; ++it) {
            int idx = it * 128 + t;
            int chan = idx >> 5, key = idx & 31;
            outp[(((size_t)b * HEADS + (chan >> 5)) * 32 + (chan & 31)) * (size_t)nk + key0 + key]
                = au[key * 132 + chan];
        }
    }
}

// MFMA flash attention partial: 1 wave/block, 32 q/wave, NO LDS, NO barriers,
// 2-iteration-deep register prefetch pipeline.
// K head-major [b][h][key][32]; V transposed [b][h][dh][key] (L2-resident
// per-XCD via bh==XCD swizzle).
__global__ void __launch_bounds__(64, 4) k_attn_mfma(
        const u16* __restrict__ qh, const u16* __restrict__ kh, const u16* __restrict__ vt,
        u16* __restrict__ pacc, float* __restrict__ pl) {
    const int lane = threadIdx.x;
    const int rl = lane & 31, hi = lane >> 5;
    const int bid = blockIdx.x;
    // XCD swizzle: 8496 = 8 x 1062; each XCD owns exactly one bh (1062 = 9 kc x 118 qt)
    const int wg = (bid & 7) * 1062 + (bid >> 3);
    const int qt = wg % NQT32;
    const int rest = wg / NQT32;
    const int kc = rest % KC;
    const int bh = rest / KC;
    const int b = bh >> 2, h = bh & 3;
    const int q0 = qt * 32;

    int qrow = q0 + rl; if (qrow > NQ - 1) qrow = NQ - 1;
    const u16* qp = qh + ((size_t)b * NQ + qrow) * 128 + h * 32;
    const bf16x8 qf0 = *(const bf16x8*)(qp + hi * 8);
    const bf16x8 qf1 = *(const bf16x8*)(qp + 16 + hi * 8);

    const int kstart = kc * KCHUNK;
    const u16* kptr = kh + ((size_t)bh * NK + kstart) * 32 + rl * 32 + hi * 8;
    const u16* vptr = vt + ((size_t)(bh * 32 + rl)) * NK + kstart + hi * 8;

    f32x16 acc, zero16;
    #pragma unroll
    for (int i = 0; i < 16; ++i) { acc[i] = 0.f; zero16[i] = 0.f; }
    f32x4 ls = {0.f, 0.f, 0.f, 0.f};

    // 2-deep register pipeline, named stages (no runtime-indexed arrays)
    bf16x8 k0a = *(const bf16x8*)(kptr);
    bf16x8 k0b = *(const bf16x8*)(kptr + 16);
    bf16x8 v0a = *(const bf16x8*)(vptr);
    bf16x8 v0b = *(const bf16x8*)(vptr + 16);
    bf16x8 k1a = *(const bf16x8*)(kptr + 1024);
    bf16x8 k1b = *(const bf16x8*)(kptr + 1024 + 16);
    bf16x8 v1a = *(const bf16x8*)(vptr + 32);
    bf16x8 v1b = *(const bf16x8*)(vptr + 32 + 16);

#define ATT_BODY(II, KA, KB, VA, VB)                                              \
    {                                                                             \
        __builtin_amdgcn_s_setprio(1);                                            \
        f32x16 s = __builtin_amdgcn_mfma_f32_32x32x16_bf16(KA, qf0, zero16, 0, 0, 0); \
        s = __builtin_amdgcn_mfma_f32_32x32x16_bf16(KB, qf1, s, 0, 0, 0);         \
        __builtin_amdgcn_s_setprio(0);                                            \
        int nid = ((II) + 2 < NIT) ? (II) + 2 : 0;                                \
        KA = *(const bf16x8*)(kptr + (size_t)nid * 1024);                         \
        KB = *(const bf16x8*)(kptr + (size_t)nid * 1024 + 16);                    \
        u32 c0, c1, c2, c3, c4, c5, c6, c7;                                       \
        {                                                                         \
            float e0, e1, e2, e3;                                                 \
            VEXP(e0, s[0]);  VEXP(e1, s[1]);  VEXP(e2, s[2]);  VEXP(e3, s[3]);    \
            CVTPK(c0, e0, e1); CVTPK(c1, e2, e3);                                 \
            ls += (f32x4){e0, e1, e2, e3};                                        \
            VEXP(e0, s[4]);  VEXP(e1, s[5]);  VEXP(e2, s[6]);  VEXP(e3, s[7]);    \
            CVTPK(c2, e0, e1); CVTPK(c3, e2, e3);                                 \
            ls += (f32x4){e0, e1, e2, e3};                                        \
            VEXP(e0, s[8]);  VEXP(e1, s[9]);  VEXP(e2, s[10]); VEXP(e3, s[11]);   \
            CVTPK(c4, e0, e1); CVTPK(c5, e2, e3);                                 \
            ls += (f32x4){e0, e1, e2, e3};                                        \
            VEXP(e0, s[12]); VEXP(e1, s[13]); VEXP(e2, s[14]); VEXP(e3, s[15]);   \
            CVTPK(c6, e0, e1); CVTPK(c7, e2, e3);                                 \
            ls += (f32x4){e0, e1, e2, e3};                                        \
        }                                                                         \
        asm("v_permlane32_swap_b32 %0, %1" : "+v"(c0), "+v"(c2));                 \
        asm("v_permlane32_swap_b32 %0, %1" : "+v"(c1), "+v"(c3));                 \
        asm("v_permlane32_swap_b32 %0, %1" : "+v"(c4), "+v"(c6));                 \
        asm("v_permlane32_swap_b32 %0, %1" : "+v"(c5), "+v"(c7));                 \
        const bf16x8 p0 = mk_frag(c0, c1, c2, c3);                                \
        const bf16x8 p1 = mk_frag(c4, c5, c6, c7);                                \
        __builtin_amdgcn_s_setprio(1);                                            \
        acc = __builtin_amdgcn_mfma_f32_32x32x16_bf16(p0, VA, acc, 0, 0, 0);      \
        acc = __builtin_amdgcn_mfma_f32_32x32x16_bf16(p1, VB, acc, 0, 0, 0);      \
        __builtin_amdgcn_s_setprio(0);                                            \
        VA = *(const bf16x8*)(vptr + (size_t)nid * 32);                           \
        VB = *(const bf16x8*)(vptr + (size_t)nid * 32 + 16);                      \
    }

    for (int ii = 0; ii + 1 < NIT; ii += 2) {
        ATT_BODY(ii, k0a, k0b, v0a, v0b);
        ATT_BODY(ii + 1, k1a, k1b, v1a, v1b);
    }
    ATT_BODY(NIT - 1, k0a, k0b, v0a, v0b);   // NIT odd: last iter uses stage 0
#undef ATT_BODY

    float lsum = (ls[0] + ls[1]) + (ls[2] + ls[3]);
    float ltot = lsum + __shfl_xor(lsum, 32);

    const int pi = bh * KC + kc;
    #pragma unroll
    for (int reg = 0; reg < 16; ++reg) {
        int qloc = (reg & 3) + 8 * (reg >> 2) + 4 * hi;
        int qq = q0 + qloc;
        if (qq < NQ) pacc[((size_t)pi * NQ + qq) * 32 + rl] = f2bf(acc[reg]);
    }
    if (hi == 0) {
        int qq = q0 + rl;
        if (qq < NQ) pl[(size_t)pi * NQ + qq] = ltot;
    }
}

// fused: combine split-K partials -> a-tile (LDS) -> proj MFMA -> +skip -> pre-LN -> zn
__global__ void __launch_bounds__(256) k_projskip(
        const u16* __restrict__ pacc, const float* __restrict__ pl,
        const u16* __restrict__ wt, const float* __restrict__ bias,
        const float* __restrict__ skip,
        const float* __restrict__ gam, const float* __restrict__ bet,
        u16* __restrict__ zn) {
    __shared__ u16 au[32 * 136];
    __shared__ float rLs[32][4];
    __shared__ float zs[32][132];
    __shared__ float smu[32], srs[32];
    const int t = threadIdx.x;
    const int g0 = blockIdx.x * 32;
    const int rows = BB * NQ;
    if (t < 128) {   // reciprocal denominators
        int row = t >> 2, h = t & 3;
        int grow = g0 + row;
        float L = 1.f;
        if (grow < rows) {
            int b = grow / NQ, qq = grow - b * NQ;
            L = 0.f;
            #pragma unroll
            for (int kc = 0; kc < KC; ++kc)
                L += pl[(size_t)((b * HEADS + h) * KC + kc) * NQ + qq];
        }
        rLs[row][h] = 1.f / L;
    }
    __syncthreads();
    #pragma unroll
    for (int it = 0; it < 16; ++it) {   // combine partials into a-tile
        int idx = it * 256 + t;
        int row = idx >> 7, col = idx & 127;
        int grow = g0 + row;
        u16 outv = 0;
        if (grow < rows) {
            int b = grow / NQ, qq = grow - b * NQ;
            int h = col >> 5, j = col & 31;
            float val = 0.f;
            #pragma unroll
            for (int kc = 0; kc < KC; ++kc)
                val += bf2f(pacc[((size_t)((b * HEADS + h) * KC + kc) * NQ + qq) * 32 + j]);
            outv = f2bf(val * rLs[row][h]);
        }
        au[row * 136 + col] = outv;
    }
    __syncthreads();
    const int lane = t & 63, wid = t >> 6;
    const int rl = lane & 31, hi = lane >> 5;
    const int c = wid * 32 + rl;
    f32x16 acc;
    #pragma unroll
    for (int i = 0; i < 16; ++i) acc[i] = 0.f;
    #pragma unroll
    for (int ks = 0; ks < 8; ++ks) {
        bf16x8 af = *(const bf16x8*)&au[rl * 136 + ks * 16 + hi * 8];
        bf16x8 bf = *(const bf16x8*)(wt + (size_t)c * 128 + ks * 16 + hi * 8);
        acc = __builtin_amdgcn_mfma_f32_32x32x16_bf16(af, bf, acc, 0, 0, 0);
    }
    const float bb = bias[c];
    #pragma unroll
    for (int reg = 0; reg < 16; ++reg) {
        int row = (reg & 3) + 8 * (reg >> 2) + 4 * hi;
        zs[row][c] = acc[reg] + bb;
    }
    __syncthreads();
    {   // skip add (channel-strided)
        const int sl = t & 31, du = t >> 5;   // du 0..7
        const int grow = g0 + sl;
        if (grow < rows) {
            const int bn = grow / MM, mm = grow % MM;
            const float* sbase = skip + (size_t)bn * 128 * MM + mm;
            for (int it = 0; it < 16; ++it) {
                int dd = it * 8 + du;
                zs[sl][dd] += sbase[(size_t)dd * MM];
            }
        }
    }
    __syncthreads();
    {   // stats, 8 threads/row
        const int r = t >> 3, p = t & 7;
        float sum = 0.f, sq = 0.f;
        for (int j = 0; j < 16; ++j) {
            float v = zs[r][p + 8 * j];
            sum += v; sq += v * v;
        }
        sum += __shfl_xor(sum, 1); sq += __shfl_xor(sq, 1);
        sum += __shfl_xor(sum, 2); sq += __shfl_xor(sq, 2);
        sum += __shfl_xor(sum, 4); sq += __shfl_xor(sq, 4);
        if (p == 0) {
            float mu = sum * (1.f / 128.f);
            float var = sq * (1.f / 128.f) - mu * mu;
            smu[r] = mu; srs[r] = rsqrtf(var + EPSV);
        }
    }
    __syncthreads();
    {
        const int cc = t & 127, rh = t >> 7;
        const float gv = gam[cc], bv = bet[cc];
        for (int i = 0; i < 16; ++i) {
            int rr = rh * 16 + i;
            int grow = g0 + rr;
            if (grow < rows)
                zn[(size_t)grow * 128 + cc] = f2bf((zs[rr][cc] - smu[rr]) * srs[rr] * gv + bv);
        }
    }
}

// hmid = gelu(zn @ w1T + b1) -> bf16
__global__ void __launch_bounds__(256) k_mlp1(
        const u16* __restrict__ zn, const u16* __restrict__ wt,
        const float* __restrict__ bias, u16* __restrict__ hmid) {
    const int t = threadIdx.x;
    const int g0 = blockIdx.x * 32;
    const int lane = t & 63, wid = t >> 6;
    const int rl = lane & 31, hi = lane >> 5;
    const int rows = BB * NQ;
    int arow = g0 + rl; if (arow > rows - 1) arow = rows - 1;
    bf16x8 afrag[8];
    #pragma unroll
    for (int ks = 0; ks < 8; ++ks)
        afrag[ks] = *(const bf16x8*)(zn + (size_t)arow * 128 + ks * 16 + hi * 8);
    #pragma unroll
    for (int tile = 0; tile < 2; ++tile) {
        const int c = wid * 64 + tile * 32 + rl;
        f32x16 acc;
        #pragma unroll
        for (int i = 0; i < 16; ++i) acc[i] = 0.f;
        #pragma unroll
        for (int ks = 0; ks < 8; ++ks) {
            bf16x8 bf = *(const bf16x8*)(wt + (size_t)c * 128 + ks * 16 + hi * 8);
            acc = __builtin_amdgcn_mfma_f32_32x32x16_bf16(afrag[ks], bf, acc, 0, 0, 0);
        }
        const float bb = bias[c];
        #pragma unroll
        for (int reg = 0; reg < 16; ++reg) {
            int row = (reg & 3) + 8 * (reg >> 2) + 4 * hi;
            int grow = g0 + row;
            if (grow < rows) {
                float x = acc[reg] + bb;
                float gl = 0.5f * x * (1.f + erff(x * 0.70710678118654752f));
                hmid[(size_t)grow * 256 + c] = f2bf(gl);
            }
        }
    }
}

// z2 = zn + hmid @ w2T + b2 ; post-LN ; transposed store fp32
__global__ void __launch_bounds__(256) k_mlp2(
        const u16* __restrict__ hmid, const u16* __restrict__ wt,
        const float* __restrict__ bias, const u16* __restrict__ zn,
        const float* __restrict__ gam, const float* __restrict__ bet,
        float* __restrict__ outp) {
    __shared__ float zt[32][132];
    __shared__ float smu[32], srs[32];
    const int t = threadIdx.x;
    const int g0 = blockIdx.x * 32;
    const int lane = t & 63, wid = t >> 6;
    const int rl = lane & 31, hi = lane >> 5;
    const int rows = BB * NQ;
    int arow = g0 + rl; if (arow > rows - 1) arow = rows - 1;
    const int c = wid * 32 + rl;
    f32x16 acc;
    #pragma unroll
    for (int i = 0; i < 16; ++i) acc[i] = 0.f;
    #pragma unroll
    for (int ks = 0; ks < 16; ++ks) {
        bf16x8 af = *(const bf16x8*)(hmid + (size_t)arow * 256 + ks * 16 + hi * 8);
        bf16x8 bf = *(const bf16x8*)(wt + (size_t)c * 256 + ks * 16 + hi * 8);
        acc = __builtin_amdgcn_mfma_f32_32x32x16_bf16(af, bf, acc, 0, 0, 0);
    }
    const float bb = bias[c];
    #pragma unroll
    for (int reg = 0; reg < 16; ++reg) {
        int row = (reg & 3) + 8 * (reg >> 2) + 4 * hi;
        zt[row][c] = acc[reg] + bb;
    }
    __syncthreads();
    {   // + zn residual
        const int cc = t & 127, rh = t >> 7;
        for (int i = 0; i < 16; ++i) {
            int rr = rh * 16 + i;
            int grow = g0 + rr;
            u16 zv = (grow < rows) ? zn[(size_t)grow * 128 + cc] : (u16)0;
            zt[rr][cc] += bf2f(zv);
        }
    }
    __syncthreads();
    {   // stats, 8 threads/row
        const int r = t >> 3, p = t & 7;
        float sum = 0.f, sq = 0.f;
        for (int j = 0; j < 16; ++j) {
            float v = zt[r][p + 8 * j];
            sum += v; sq += v * v;
        }
        sum += __shfl_xor(sum, 1); sq += __shfl_xor(sq, 1);
        sum += __shfl_xor(sum, 2); sq += __shfl_xor(sq, 2);
        sum += __shfl_xor(sum, 4); sq += __shfl_xor(sq, 4);
        if (p == 0) {
            float mu = sum * (1.f / 128.f);
            float var = sq * (1.f / 128.f) - mu * mu;
            smu[r] = mu; srs[r] = rsqrtf(var + EPSV);
        }
    }
    __syncthreads();
    {   // transposed store
        const int sl = t & 31, du = t >> 5;   // du 0..7
        const int grow = g0 + sl;
        if (grow < rows) {
            const int bn = grow / MM, mm = grow % MM;
            const float mu = smu[sl], rs = srs[sl];
            float* obase = outp + (size_t)bn * 128 * MM + mm;
            for (int it = 0; it < 16; ++it) {
                int dd = it * 8 + du;
                obase[(size_t)dd * MM] = (zt[sl][dd] - mu) * rs * gam[dd] + bet[dd];
            }
        }
    }
}

extern "C" void kernel_launch(void* const* d_in, const int* in_sizes, int n_in,
                              void* d_out, int out_size, void* d_ws, size_t ws_size,
                              hipStream_t stream) {
    const float* q      = (const float*)d_in[0];
    const float* k      = (const float*)d_in[1];
    const float* v      = (const float*)d_in[2];
    const float* skip   = (const float*)d_in[3];
    const float* ln_q_g = (const float*)d_in[4];
    const float* ln_q_b = (const float*)d_in[5];
    const float* wq     = (const float*)d_in[6];
    const float* bq     = (const float*)d_in[7];
    const float* ln_k_g = (const float*)d_in[8];
    const float* ln_k_b = (const float*)d_in[9];
    const float* wk     = (const float*)d_in[10];
    const float* bk     = (const float*)d_in[11];
    const float* ln_v_g = (const float*)d_in[12];
    const float* ln_v_b = (const float*)d_in[13];
    const float* wv     = (const float*)d_in[14];
    const float* bv     = (const float*)d_in[15];
    const float* proj_w = (const float*)d_in[16];
    const float* proj_b = (const float*)d_in[17];
    const float* pre_g  = (const float*)d_in[18];
    const float* pre_b  = (const float*)d_in[19];
    const float* mlp_w1 = (const float*)d_in[20];
    const float* mlp_b1 = (const float*)d_in[21];
    const float* mlp_w2 = (const float*)d_in[22];
    const float* mlp_b2 = (const float*)d_in[23];
    const float* post_g = (const float*)d_in[24];
    const float* post_b = (const float*)d_in[25];

    float* ws   = (float*)d_ws;
    float* outp = (float*)d_out;

    u16* qh   = (u16*)(ws + OFF_QH);
    u16* kh   = (u16*)(ws + OFF_KH);
    u16* vt   = (u16*)(ws + OFF_VH);
    u16* pacc = (u16*)(ws + OFF_PACC);
    float* pl   = ws + OFF_PL;
    u16* zn   = (u16*)(ws + OFF_ZN);
    u16* hmid = (u16*)(ws + OFF_HMID);
    u16* wtb  = (u16*)(ws + OFF_WTB);

    k_prep<<<512, 256, 0, stream>>>(wq, wk, wv, proj_w, mlp_w1, mlp_w2, wtb);
    k_lnproj<<<235, 128, 0, stream>>>(q, MM, BB * NQ, ln_q_g, ln_q_b, wtb + WT_Q, bq, QPRESCALE, 0, NK, qh);
    k_lnproj<<<630, 128, 0, stream>>>(k, HWSZ, BB * NK, ln_k_g, ln_k_b, wtb + WT_K, bk, 1.0f, 1, NK, kh);
    k_lnproj<<<630, 128, 0, stream>>>(v, HWSZ, BB * NK, ln_v_g, ln_v_b, wtb + WT_V, bv, 1.0f, 2, NK, vt);
    k_attn_mfma<<<BB * HEADS * NQT32 * KC, 64, 0, stream>>>(qh, kh, vt, pacc, pl);
    k_projskip<<<235, 256, 0, stream>>>(pacc, pl, wtb + WT_PROJ, proj_b, skip, pre_g, pre_b, zn);
    k_mlp1<<<235, 256, 0, stream>>>(zn, wtb + WT_W1, mlp_b1, hmid);
    k_mlp2<<<235, 256, 0, stream>>>(hmid, wtb + WT_W2, mlp_b2, zn, post_g, post_b, outp);
}

// Round 11
// 158.890 us; speedup vs baseline: 1.0814x; 1.0814x over previous
//
#include <hip/hip_runtime.h>
#include <hip/hip_bf16.h>
#include <math.h>

typedef __attribute__((ext_vector_type(8))) short bf16x8;
typedef __attribute__((ext_vector_type(4))) float f32x4;
typedef __attribute__((ext_vector_type(16))) float f32x16;
typedef unsigned short u16;
typedef unsigned int u32;

#define BB 2
#define NN 6
#define MM 625
#define HWSZ 1680
#define NQ 3750
#define NK 10080
#define HEADS 4
#define EPSV 1e-5f
#define KC 9
#define KCHUNK 1120
#define NIT 35               // KCHUNK/32 exact, no fake keys
#define NQT64 59             // ceil(3750/64)
#define QPRESCALE 0.25503489f   // (1/sqrt(32)) * log2(e)

// ---- workspace offsets (floats) ----
#define OFF_QH   0          // bf16 960000  u16 -> 480000 fl  (row-major [row][128])
#define OFF_KH   480000     // bf16 2580480 u16 -> 1290240 fl (head-major [b][h][key][32])
#define OFF_VH   1770240    // bf16 2580480 u16                (transposed [b][h][dh][key])
#define OFF_PACC 3060480    // bf16 2*4*9*3750*32 u16 -> 4320000 fl
#define OFF_PL   7380480    // 270000 fl
#define OFF_ZN   8130480    // bf16 960000 u16 -> 480000 fl
#define OFF_HMID 8610480    // bf16 1920000 u16 -> 960000 fl
#define OFF_WTB  9570480    // 131072 u16 -> 65536 fl ; end 9636016

// u16 offsets inside WTB
#define WT_Q    0
#define WT_K    16384
#define WT_V    32768
#define WT_PROJ 49152
#define WT_W1   65536      // [256][128]
#define WT_W2   98304      // [128][256]

#define VEXP(d, s_) asm("v_exp_f32 %0, %1\n\ts_nop 0" : "=v"(d) : "v"(s_))
#define CVTPK(d, a, b) asm("v_cvt_pk_bf16_f32 %0, %1, %2" : "=v"(d) : "v"(a), "v"(b))

__device__ inline u16 f2bf(float f) {
    __hip_bfloat16 h = __float2bfloat16(f);
    return *reinterpret_cast<u16*>(&h);
}
__device__ inline float bf2f(u16 u) {
    u32 x = ((u32)u) << 16;
    return *reinterpret_cast<float*>(&x);
}
__device__ inline bf16x8 mk_frag(u32 a, u32 b, u32 c, u32 d) {
    union { u32 u[4]; bf16x8 v; } x;
    x.u[0] = a; x.u[1] = b; x.u[2] = c; x.u[3] = d;
    return x.v;
}

// weights -> bf16 transposed
__global__ void __launch_bounds__(256) k_prep(
        const float* __restrict__ wq, const float* __restrict__ wk,
        const float* __restrict__ wv, const float* __restrict__ pw,
        const float* __restrict__ w1, const float* __restrict__ w2,
        u16* __restrict__ wtb) {
    int idx = blockIdx.x * 256 + threadIdx.x;   // 131072 exact
    float v;
    if (idx < 65536) {
        const float* src = (idx < 16384) ? wq : (idx < 32768) ? wk
                         : (idx < 49152) ? wv : pw;
        int r = idx & 16383;
        int c = r >> 7, kk = r & 127;
        v = src[kk * 128 + c];
    } else if (idx < 98304) {
        int r = idx - 65536;
        int c = r >> 7, kk = r & 127;
        v = w1[kk * 256 + c];
    } else {
        int r = idx - 98304;
        int c = r >> 8, kk = r & 255;
        v = w2[kk * 128 + c];
    }
    wtb[idx] = f2bf(v);
}

// LN (over 128 ch, channel-strided input) + MFMA 128x128 projection -> bf16.
// mode 0: row-major [row][128] ; mode 1: head-major [b][h][key][32] ;
// mode 2: transposed head-major [b][h][dh][key]  (for V^T)
__global__ void __launch_bounds__(128) k_lnproj(const float* __restrict__ x, int S, int rows,
        const float* __restrict__ gam, const float* __restrict__ bet,
        const u16* __restrict__ wt, const float* __restrict__ bias,
        float oscale, int mode, int nk, u16* __restrict__ outp) {
    __shared__ float xs[32][132];
    __shared__ float smu[32], srs[32];
    const int t = threadIdx.x;
    const int g0 = blockIdx.x * 32;
    {   // transposed coalesced load
        const int sl = t & 31, du = t >> 5;
        const int grow = g0 + sl;
        const bool vload = grow < rows;
        const int bn = grow / S, ss = grow % S;
        const float* xbase = x + (size_t)bn * 128 * S + ss;
        for (int it = 0; it < 32; ++it) {
            int dd = it * 4 + du;
            xs[sl][dd] = vload ? xbase[(size_t)dd * S] : 0.f;
        }
    }
    __syncthreads();
    {   // stats, 4 threads/row
        const int r = t >> 2, p = t & 3;
        float sum = 0.f, sq = 0.f;
        for (int j = 0; j < 32; ++j) {
            float v = xs[r][p + 4 * j];
            sum += v; sq += v * v;
        }
        sum += __shfl_xor(sum, 1); sq += __shfl_xor(sq, 1);
        sum += __shfl_xor(sum, 2); sq += __shfl_xor(sq, 2);
        if (p == 0) {
            float mu = sum * (1.f / 128.f);
            float var = sq * (1.f / 128.f) - mu * mu;
            smu[r] = mu;
            srs[r] = rsqrtf(var + EPSV);
        }
    }
    __syncthreads();
    {   // normalize in LDS
        const float gv = gam[t], bv = bet[t];
        for (int rr = 0; rr < 32; ++rr)
            xs[rr][t] = (xs[rr][t] - smu[rr]) * srs[rr] * gv + bv;
    }
    __syncthreads();
    // MFMA GEMM: wave wid covers cols wid*64..+63
    const int lane = t & 63, wid = t >> 6;
    const int rl = lane & 31, hi = lane >> 5;
    bf16x8 afrag[8];
    #pragma unroll
    for (int ks = 0; ks < 8; ++ks) {
        float4 u = *(const float4*)&xs[rl][ks * 16 + hi * 8];
        float4 w = *(const float4*)&xs[rl][ks * 16 + hi * 8 + 4];
        u32 d0, d1, d2, d3;
        CVTPK(d0, u.x, u.y);
        CVTPK(d1, u.z, u.w);
        CVTPK(d2, w.x, w.y);
        CVTPK(d3, w.z, w.w);
        afrag[ks] = mk_frag(d0, d1, d2, d3);
    }
    u16* au = (u16*)&xs[0][0];      // alias, used only in mode 2
    if (mode == 2) __syncthreads(); // all waves done reading xs
    #pragma unroll
    for (int tile = 0; tile < 2; ++tile) {
        const int c = wid * 64 + tile * 32 + rl;
        f32x16 acc;
        #pragma unroll
        for (int i = 0; i < 16; ++i) acc[i] = 0.f;
        #pragma unroll
        for (int ks = 0; ks < 8; ++ks) {
            bf16x8 bfrag = *(const bf16x8*)(wt + (size_t)c * 128 + ks * 16 + hi * 8);
            acc = __builtin_amdgcn_mfma_f32_32x32x16_bf16(afrag[ks], bfrag, acc, 0, 0, 0);
        }
        const float bb = bias[c];
        #pragma unroll
        for (int reg = 0; reg < 16; ++reg) {
            int row = (reg & 3) + 8 * (reg >> 2) + 4 * hi;
            int grow = g0 + row;
            u16 val = f2bf((acc[reg] + bb) * oscale);
            if (mode == 2) {
                au[row * 132 + c] = val;
            } else if (mode == 1) {
                if (grow < rows) {
                    int b = (grow >= nk) ? 1 : 0;
                    int key = grow - b * nk;
                    outp[(((size_t)b * HEADS + (c >> 5)) * nk + key) * 32 + (c & 31)] = val;
                }
            } else {
                if (grow < rows) outp[(size_t)grow * 128 + c] = val;
            }
        }
    }
    if (mode == 2) {
        __syncthreads();
        const int b = (g0 >= nk) ? 1 : 0;
        const int key0 = g0 - b * nk;
        // coalesced transposed store: lanes sweep key
        for (int it = 0; it < 32; ++it) {
            int idx = it * 128 + t;
            int chan = idx >> 5, key = idx & 31;
            outp[(((size_t)b * HEADS + (chan >> 5)) * 32 + (chan & 31)) * (size_t)nk + key0 + key]
                = au[key * 132 + chan];
        }
    }
}

// MFMA flash attention partial: 1 wave/block, 64 q/wave (2 tiles), NO LDS,
// NO barriers. Phase-pipelined: scores carried one iter ahead so QK^T(ii+1)
// (MFMA pipe) overlaps softmax(ii) (VALU pipe). K loaded 2-3 iters ahead,
// V 2 iters ahead, all named register stages.
__global__ void __launch_bounds__(64, 3) k_attn_mfma(
        const u16* __restrict__ qh, const u16* __restrict__ kh, const u16* __restrict__ vt,
        u16* __restrict__ pacc, float* __restrict__ pl) {
    const int lane = threadIdx.x;
    const int rl = lane & 31, hi = lane >> 5;
    const int bid = blockIdx.x;
    // XCD swizzle: 4248 = 8 x 531; each XCD owns exactly one bh (531 = 9 kc x 59 qt)
    const int wg = (bid & 7) * 531 + (bid >> 3);
    const int qt = wg % NQT64;
    const int rest = wg / NQT64;
    const int kc = rest % KC;
    const int bh = rest / KC;
    const int b = bh >> 2, h = bh & 3;
    const int q0A = qt * 64, q0B = q0A + 32;

    int qrowA = q0A + rl; if (qrowA > NQ - 1) qrowA = NQ - 1;
    int qrowB = q0B + rl; if (qrowB > NQ - 1) qrowB = NQ - 1;
    const u16* qpA = qh + ((size_t)b * NQ + qrowA) * 128 + h * 32;
    const u16* qpB = qh + ((size_t)b * NQ + qrowB) * 128 + h * 32;
    const bf16x8 qfA0 = *(const bf16x8*)(qpA + hi * 8);
    const bf16x8 qfA1 = *(const bf16x8*)(qpA + 16 + hi * 8);
    const bf16x8 qfB0 = *(const bf16x8*)(qpB + hi * 8);
    const bf16x8 qfB1 = *(const bf16x8*)(qpB + 16 + hi * 8);

    const int kstart = kc * KCHUNK;
    const u16* kptr = kh + ((size_t)bh * NK + kstart) * 32 + rl * 32 + hi * 8;
    const u16* vptr = vt + ((size_t)(bh * 32 + rl)) * NK + kstart + hi * 8;

    f32x16 accA, accB, zero16;
    #pragma unroll
    for (int i = 0; i < 16; ++i) { accA[i] = 0.f; accB[i] = 0.f; zero16[i] = 0.f; }
    f32x4 lsA = {0.f, 0.f, 0.f, 0.f}, lsB = {0.f, 0.f, 0.f, 0.f};

    // register stages
    bf16x8 k0a = *(const bf16x8*)(kptr);
    bf16x8 k0b = *(const bf16x8*)(kptr + 16);
    bf16x8 k1a = *(const bf16x8*)(kptr + 1024);
    bf16x8 k1b = *(const bf16x8*)(kptr + 1024 + 16);
    bf16x8 v0a = *(const bf16x8*)(vptr);
    bf16x8 v0b = *(const bf16x8*)(vptr + 16);
    bf16x8 v1a = *(const bf16x8*)(vptr + 32);
    bf16x8 v1b = *(const bf16x8*)(vptr + 32 + 16);

    // scores for iter 0
    f32x16 sA = __builtin_amdgcn_mfma_f32_32x32x16_bf16(k0a, qfA0, zero16, 0, 0, 0);
    sA = __builtin_amdgcn_mfma_f32_32x32x16_bf16(k0b, qfA1, sA, 0, 0, 0);
    f32x16 sB = __builtin_amdgcn_mfma_f32_32x32x16_bf16(k0a, qfB0, zero16, 0, 0, 0);
    sB = __builtin_amdgcn_mfma_f32_32x32x16_bf16(k0b, qfB1, sB, 0, 0, 0);
    // k0 slot free -> K(2)
    k0a = *(const bf16x8*)(kptr + 2048);
    k0b = *(const bf16x8*)(kptr + 2048 + 16);

// softmax of current scores sA/sB -> declares PA0, PA1, PB0, PB1 in scope
#define SMAX()                                                                    \
    u32 a0, a1, a2, a3, a4, a5, a6, a7;                                           \
    u32 b0, b1, b2, b3, b4, b5, b6, b7;                                           \
    {                                                                             \
        float e0, e1, e2, e3;                                                     \
        VEXP(e0, sA[0]);  VEXP(e1, sA[1]);  VEXP(e2, sA[2]);  VEXP(e3, sA[3]);    \
        CVTPK(a0, e0, e1); CVTPK(a1, e2, e3);                                     \
        lsA += (f32x4){e0, e1, e2, e3};                                           \
        VEXP(e0, sA[4]);  VEXP(e1, sA[5]);  VEXP(e2, sA[6]);  VEXP(e3, sA[7]);    \
        CVTPK(a2, e0, e1); CVTPK(a3, e2, e3);                                     \
        lsA += (f32x4){e0, e1, e2, e3};                                           \
        VEXP(e0, sA[8]);  VEXP(e1, sA[9]);  VEXP(e2, sA[10]); VEXP(e3, sA[11]);   \
        CVTPK(a4, e0, e1); CVTPK(a5, e2, e3);                                     \
        lsA += (f32x4){e0, e1, e2, e3};                                           \
        VEXP(e0, sA[12]); VEXP(e1, sA[13]); VEXP(e2, sA[14]); VEXP(e3, sA[15]);   \
        CVTPK(a6, e0, e1); CVTPK(a7, e2, e3);                                     \
        lsA += (f32x4){e0, e1, e2, e3};                                           \
        VEXP(e0, sB[0]);  VEXP(e1, sB[1]);  VEXP(e2, sB[2]);  VEXP(e3, sB[3]);    \
        CVTPK(b0, e0, e1); CVTPK(b1, e2, e3);                                     \
        lsB += (f32x4){e0, e1, e2, e3};                                           \
        VEXP(e0, sB[4]);  VEXP(e1, sB[5]);  VEXP(e2, sB[6]);  VEXP(e3, sB[7]);    \
        CVTPK(b2, e0, e1); CVTPK(b3, e2, e3);                                     \
        lsB += (f32x4){e0, e1, e2, e3};                                           \
        VEXP(e0, sB[8]);  VEXP(e1, sB[9]);  VEXP(e2, sB[10]); VEXP(e3, sB[11]);   \
        CVTPK(b4, e0, e1); CVTPK(b5, e2, e3);                                     \
        lsB += (f32x4){e0, e1, e2, e3};                                           \
        VEXP(e0, sB[12]); VEXP(e1, sB[13]); VEXP(e2, sB[14]); VEXP(e3, sB[15]);   \
        CVTPK(b6, e0, e1); CVTPK(b7, e2, e3);                                     \
        lsB += (f32x4){e0, e1, e2, e3};                                           \
    }                                                                             \
    asm("v_permlane32_swap_b32 %0, %1" : "+v"(a0), "+v"(a2));                     \
    asm("v_permlane32_swap_b32 %0, %1" : "+v"(a1), "+v"(a3));                     \
    asm("v_permlane32_swap_b32 %0, %1" : "+v"(a4), "+v"(a6));                     \
    asm("v_permlane32_swap_b32 %0, %1" : "+v"(a5), "+v"(a7));                     \
    asm("v_permlane32_swap_b32 %0, %1" : "+v"(b0), "+v"(b2));                     \
    asm("v_permlane32_swap_b32 %0, %1" : "+v"(b1), "+v"(b3));                     \
    asm("v_permlane32_swap_b32 %0, %1" : "+v"(b4), "+v"(b6));                     \
    asm("v_permlane32_swap_b32 %0, %1" : "+v"(b5), "+v"(b7));                     \
    const bf16x8 PA0 = mk_frag(a0, a1, a2, a3);                                   \
    const bf16x8 PA1 = mk_frag(a4, a5, a6, a7);                                   \
    const bf16x8 PB0 = mk_frag(b0, b1, b2, b3);                                   \
    const bf16x8 PB1 = mk_frag(b4, b5, b6, b7);

// body for iter II: issue QK(II+1) from (KA,KB) first, overlap softmax(II),
// then PV(II) with (VA,VB). Reload KA<-K(II+3), VA<-V(II+2).
#define BODY(II, KA, KB, VA, VB)                                                  \
    {                                                                             \
        __builtin_amdgcn_s_setprio(1);                                            \
        f32x16 sAn = __builtin_amdgcn_mfma_f32_32x32x16_bf16(KA, qfA0, zero16, 0, 0, 0); \
        sAn = __builtin_amdgcn_mfma_f32_32x32x16_bf16(KB, qfA1, sAn, 0, 0, 0);    \
        f32x16 sBn = __builtin_amdgcn_mfma_f32_32x32x16_bf16(KA, qfB0, zero16, 0, 0, 0); \
        sBn = __builtin_amdgcn_mfma_f32_32x32x16_bf16(KB, qfB1, sBn, 0, 0, 0);    \
        __builtin_amdgcn_s_setprio(0);                                            \
        int kid = ((II) + 3 < NIT) ? (II) + 3 : 0;                                \
        KA = *(const bf16x8*)(kptr + (size_t)kid * 1024);                         \
        KB = *(const bf16x8*)(kptr + (size_t)kid * 1024 + 16);                    \
        SMAX()                                                                    \
        __builtin_amdgcn_s_setprio(1);                                            \
        accA = __builtin_amdgcn_mfma_f32_32x32x16_bf16(PA0, VA, accA, 0, 0, 0);   \
        accA = __builtin_amdgcn_mfma_f32_32x32x16_bf16(PA1, VB, accA, 0, 0, 0);   \
        accB = __builtin_amdgcn_mfma_f32_32x32x16_bf16(PB0, VA, accB, 0, 0, 0);   \
        accB = __builtin_amdgcn_mfma_f32_32x32x16_bf16(PB1, VB, accB, 0, 0, 0);   \
        __builtin_amdgcn_s_setprio(0);                                            \
        int vid = ((II) + 2 < NIT) ? (II) + 2 : 0;                                \
        VA = *(const bf16x8*)(vptr + (size_t)vid * 32);                           \
        VB = *(const bf16x8*)(vptr + (size_t)vid * 32 + 16);                      \
        sA = sAn; sB = sBn;                                                       \
    }

    for (int ii = 0; ii < NIT - 1; ii += 2) {
        BODY(ii, k1a, k1b, v0a, v0b);
        BODY(ii + 1, k0a, k0b, v1a, v1b);
    }
    {   // tail iter NIT-1 (even stage: v0 holds V(NIT-1)); no next-score needed
        SMAX()
        __builtin_amdgcn_s_setprio(1);
        accA = __builtin_amdgcn_mfma_f32_32x32x16_bf16(PA0, v0a, accA, 0, 0, 0);
        accA = __builtin_amdgcn_mfma_f32_32x32x16_bf16(PA1, v0b, accA, 0, 0, 0);
        accB = __builtin_amdgcn_mfma_f32_32x32x16_bf16(PB0, v0a, accB, 0, 0, 0);
        accB = __builtin_amdgcn_mfma_f32_32x32x16_bf16(PB1, v0b, accB, 0, 0, 0);
        __builtin_amdgcn_s_setprio(0);
    }
#undef BODY
#undef SMAX

    float lsumA = (lsA[0] + lsA[1]) + (lsA[2] + lsA[3]);
    float lsumB = (lsB[0] + lsB[1]) + (lsB[2] + lsB[3]);
    float ltotA = lsumA + __shfl_xor(lsumA, 32);
    float ltotB = lsumB + __shfl_xor(lsumB, 32);

    const int pi = bh * KC + kc;
    #pragma unroll
    for (int reg = 0; reg < 16; ++reg) {
        int qloc = (reg & 3) + 8 * (reg >> 2) + 4 * hi;
        int qqA = q0A + qloc;
        int qqB = q0B + qloc;
        if (qqA < NQ) pacc[((size_t)pi * NQ + qqA) * 32 + rl] = f2bf(accA[reg]);
        if (qqB < NQ) pacc[((size_t)pi * NQ + qqB) * 32 + rl] = f2bf(accB[reg]);
    }
    if (hi == 0) {
        int qqA = q0A + rl, qqB = q0B + rl;
        if (qqA < NQ) pl[(size_t)pi * NQ + qqA] = ltotA;
        if (qqB < NQ) pl[(size_t)pi * NQ + qqB] = ltotB;
    }
}

// fused: combine split-K partials -> a-tile (LDS) -> proj MFMA -> +skip -> pre-LN -> zn
__global__ void __launch_bounds__(256) k_projskip(
        const u16* __restrict__ pacc, const float* __restrict__ pl,
        const u16* __restrict__ wt, const float* __restrict__ bias,
        const float* __restrict__ skip,
        const float* __restrict__ gam, const float* __restrict__ bet,
        u16* __restrict__ zn) {
    __shared__ u16 au[32 * 136];
    __shared__ float rLs[32][4];
    __shared__ float zs[32][132];
    __shared__ float smu[32], srs[32];
    const int t = threadIdx.x;
    const int g0 = blockIdx.x * 32;
    const int rows = BB * NQ;
    if (t < 128) {   // reciprocal denominators
        int row = t >> 2, h = t & 3;
        int grow = g0 + row;
        float L = 1.f;
        if (grow < rows) {
            int b = grow / NQ, qq = grow - b * NQ;
            L = 0.f;
            #pragma unroll
            for (int kc = 0; kc < KC; ++kc)
                L += pl[(size_t)((b * HEADS + h) * KC + kc) * NQ + qq];
        }
        rLs[row][h] = 1.f / L;
    }
    __syncthreads();
    #pragma unroll
    for (int it = 0; it < 16; ++it) {   // combine partials into a-tile
        int idx = it * 256 + t;
        int row = idx >> 7, col = idx & 127;
        int grow = g0 + row;
        u16 outv = 0;
        if (grow < rows) {
            int b = grow / NQ, qq = grow - b * NQ;
            int h = col >> 5, j = col & 31;
            float val = 0.f;
            #pragma unroll
            for (int kc = 0; kc < KC; ++kc)
                val += bf2f(pacc[((size_t)((b * HEADS + h) * KC + kc) * NQ + qq) * 32 + j]);
            outv = f2bf(val * rLs[row][h]);
        }
        au[row * 136 + col] = outv;
    }
    __syncthreads();
    const int lane = t & 63, wid = t >> 6;
    const int rl = lane & 31, hi = lane >> 5;
    const int c = wid * 32 + rl;
    f32x16 acc;
    #pragma unroll
    for (int i = 0; i < 16; ++i) acc[i] = 0.f;
    #pragma unroll
    for (int ks = 0; ks < 8; ++ks) {
        bf16x8 af = *(const bf16x8*)&au[rl * 136 + ks * 16 + hi * 8];
        bf16x8 bf = *(const bf16x8*)(wt + (size_t)c * 128 + ks * 16 + hi * 8);
        acc = __builtin_amdgcn_mfma_f32_32x32x16_bf16(af, bf, acc, 0, 0, 0);
    }
    const float bb = bias[c];
    #pragma unroll
    for (int reg = 0; reg < 16; ++reg) {
        int row = (reg & 3) + 8 * (reg >> 2) + 4 * hi;
        zs[row][c] = acc[reg] + bb;
    }
    __syncthreads();
    {   // skip add (channel-strided)
        const int sl = t & 31, du = t >> 5;   // du 0..7
        const int grow = g0 + sl;
        if (grow < rows) {
            const int bn = grow / MM, mm = grow % MM;
            const float* sbase = skip + (size_t)bn * 128 * MM + mm;
            for (int it = 0; it < 16; ++it) {
                int dd = it * 8 + du;
                zs[sl][dd] += sbase[(size_t)dd * MM];
            }
        }
    }
    __syncthreads();
    {   // stats, 8 threads/row
        const int r = t >> 3, p = t & 7;
        float sum = 0.f, sq = 0.f;
        for (int j = 0; j < 16; ++j) {
            float v = zs[r][p + 8 * j];
            sum += v; sq += v * v;
        }
        sum += __shfl_xor(sum, 1); sq += __shfl_xor(sq, 1);
        sum += __shfl_xor(sum, 2); sq += __shfl_xor(sq, 2);
        sum += __shfl_xor(sum, 4); sq += __shfl_xor(sq, 4);
        if (p == 0) {
            float mu = sum * (1.f / 128.f);
            float var = sq * (1.f / 128.f) - mu * mu;
            smu[r] = mu; srs[r] = rsqrtf(var + EPSV);
        }
    }
    __syncthreads();
    {
        const int cc = t & 127, rh = t >> 7;
        const float gv = gam[cc], bv = bet[cc];
        for (int i = 0; i < 16; ++i) {
            int rr = rh * 16 + i;
            int grow = g0 + rr;
            if (grow < rows)
                zn[(size_t)grow * 128 + cc] = f2bf((zs[rr][cc] - smu[rr]) * srs[rr] * gv + bv);
        }
    }
}

// hmid = gelu(zn @ w1T + b1) -> bf16
__global__ void __launch_bounds__(256) k_mlp1(
        const u16* __restrict__ zn, const u16* __restrict__ wt,
        const float* __restrict__ bias, u16* __restrict__ hmid) {
    const int t = threadIdx.x;
    const int g0 = blockIdx.x * 32;
    const int lane = t & 63, wid = t >> 6;
    const int rl = lane & 31, hi = lane >> 5;
    const int rows = BB * NQ;
    int arow = g0 + rl; if (arow > rows - 1) arow = rows - 1;
    bf16x8 afrag[8];
    #pragma unroll
    for (int ks = 0; ks < 8; ++ks)
        afrag[ks] = *(const bf16x8*)(zn + (size_t)arow * 128 + ks * 16 + hi * 8);
    #pragma unroll
    for (int tile = 0; tile < 2; ++tile) {
        const int c = wid * 64 + tile * 32 + rl;
        f32x16 acc;
        #pragma unroll
        for (int i = 0; i < 16; ++i) acc[i] = 0.f;
        #pragma unroll
        for (int ks = 0; ks < 8; ++ks) {
            bf16x8 bf = *(const bf16x8*)(wt + (size_t)c * 128 + ks * 16 + hi * 8);
            acc = __builtin_amdgcn_mfma_f32_32x32x16_bf16(afrag[ks], bf, acc, 0, 0, 0);
        }
        const float bb = bias[c];
        #pragma unroll
        for (int reg = 0; reg < 16; ++reg) {
            int row = (reg & 3) + 8 * (reg >> 2) + 4 * hi;
            int grow = g0 + row;
            if (grow < rows) {
                float x = acc[reg] + bb;
                float gl = 0.5f * x * (1.f + erff(x * 0.70710678118654752f));
                hmid[(size_t)grow * 256 + c] = f2bf(gl);
            }
        }
    }
}

// z2 = zn + hmid @ w2T + b2 ; post-LN ; transposed store fp32
__global__ void __launch_bounds__(256) k_mlp2(
        const u16* __restrict__ hmid, const u16* __restrict__ wt,
        const float* __restrict__ bias, const u16* __restrict__ zn,
        const float* __restrict__ gam, const float* __restrict__ bet,
        float* __restrict__ outp) {
    __shared__ float zt[32][132];
    __shared__ float smu[32], srs[32];
    const int t = threadIdx.x;
    const int g0 = blockIdx.x * 32;
    const int lane = t & 63, wid = t >> 6;
    const int rl = lane & 31, hi = lane >> 5;
    const int rows = BB * NQ;
    int arow = g0 + rl; if (arow > rows - 1) arow = rows - 1;
    const int c = wid * 32 + rl;
    f32x16 acc;
    #pragma unroll
    for (int i = 0; i < 16; ++i) acc[i] = 0.f;
    #pragma unroll
    for (int ks = 0; ks < 16; ++ks) {
        bf16x8 af = *(const bf16x8*)(hmid + (size_t)arow * 256 + ks * 16 + hi * 8);
        bf16x8 bf = *(const bf16x8*)(wt + (size_t)c * 256 + ks * 16 + hi * 8);
        acc = __builtin_amdgcn_mfma_f32_32x32x16_bf16(af, bf, acc, 0, 0, 0);
    }
    const float bb = bias[c];
    #pragma unroll
    for (int reg = 0; reg < 16; ++reg) {
        int row = (reg & 3) + 8 * (reg >> 2) + 4 * hi;
        zt[row][c] = acc[reg] + bb;
    }
    __syncthreads();
    {   // + zn residual
        const int cc = t & 127, rh = t >> 7;
        for (int i = 0; i < 16; ++i) {
            int rr = rh * 16 + i;
            int grow = g0 + rr;
            u16 zv = (grow < rows) ? zn[(size_t)grow * 128 + cc] : (u16)0;
            zt[rr][cc] += bf2f(zv);
        }
    }
    __syncthreads();
    {   // stats, 8 threads/row
        const int r = t >> 3, p = t & 7;
        float sum = 0.f, sq = 0.f;
        for (int j = 0; j < 16; ++j) {
            float v = zt[r][p + 8 * j];
            sum += v; sq += v * v;
        }
        sum += __shfl_xor(sum, 1); sq += __shfl_xor(sq, 1);
        sum += __shfl_xor(sum, 2); sq += __shfl_xor(sq, 2);
        sum += __shfl_xor(sum, 4); sq += __shfl_xor(sq, 4);
        if (p == 0) {
            float mu = sum * (1.f / 128.f);
            float var = sq * (1.f / 128.f) - mu * mu;
            smu[r] = mu; srs[r] = rsqrtf(var + EPSV);
        }
    }
    __syncthreads();
    {   // transposed store
        const int sl = t & 31, du = t >> 5;   // du 0..7
        const int grow = g0 + sl;
        if (grow < rows) {
            const int bn = grow / MM, mm = grow % MM;
            const float mu = smu[sl], rs = srs[sl];
            float* obase = outp + (size_t)bn * 128 * MM + mm;
            for (int it = 0; it < 16; ++it) {
                int dd = it * 8 + du;
                obase[(size_t)dd * MM] = (zt[sl][dd] - mu) * rs * gam[dd] + bet[dd];
            }
        }
    }
}

extern "C" void kernel_launch(void* const* d_in, const int* in_sizes, int n_in,
                              void* d_out, int out_size, void* d_ws, size_t ws_size,
                              hipStream_t stream) {
    const float* q      = (const float*)d_in[0];
    const float* k      = (const float*)d_in[1];
    const float* v      = (const float*)d_in[2];
    const float* skip   = (const float*)d_in[3];
    const float* ln_q_g = (const float*)d_in[4];
    const float* ln_q_b = (const float*)d_in[5];
    const float* wq     = (const float*)d_in[6];
    const float* bq     = (const float*)d_in[7];
    const float* ln_k_g = (const float*)d_in[8];
    const float* ln_k_b = (const float*)d_in[9];
    const float* wk     = (const float*)d_in[10];
    const float* bk     = (const float*)d_in[11];
    const float* ln_v_g = (const float*)d_in[12];
    const float* ln_v_b = (const float*)d_in[13];
    const float* wv     = (const float*)d_in[14];
    const float* bv     = (const float*)d_in[15];
    const float* proj_w = (const float*)d_in[16];
    const float* proj_b = (const float*)d_in[17];
    const float* pre_g  = (const float*)d_in[18];
    const float* pre_b  = (const float*)d_in[19];
    const float* mlp_w1 = (const float*)d_in[20];
    const float* mlp_b1 = (const float*)d_in[21];
    const float* mlp_w2 = (const float*)d_in[22];
    const float* mlp_b2 = (const float*)d_in[23];
    const float* post_g = (const float*)d_in[24];
    const float* post_b = (const float*)d_in[25];

    float* ws   = (float*)d_ws;
    float* outp = (float*)d_out;

    u16* qh   = (u16*)(ws + OFF_QH);
    u16* kh   = (u16*)(ws + OFF_KH);
    u16* vt   = (u16*)(ws + OFF_VH);
    u16* pacc = (u16*)(ws + OFF_PACC);
    float* pl   = ws + OFF_PL;
    u16* zn   = (u16*)(ws + OFF_ZN);
    u16* hmid = (u16*)(ws + OFF_HMID);
    u16* wtb  = (u16*)(ws + OFF_WTB);

    k_prep<<<512, 256, 0, stream>>>(wq, wk, wv, proj_w, mlp_w1, mlp_w2, wtb);
    k_lnproj<<<235, 128, 0, stream>>>(q, MM, BB * NQ, ln_q_g, ln_q_b, wtb + WT_Q, bq, QPRESCALE, 0, NK, qh);
    k_lnproj<<<630, 128, 0, stream>>>(k, HWSZ, BB * NK, ln_k_g, ln_k_b, wtb + WT_K, bk, 1.0f, 1, NK, kh);
    k_lnproj<<<630, 128, 0, stream>>>(v, HWSZ, BB * NK, ln_v_g, ln_v_b, wtb + WT_V, bv, 1.0f, 2, NK, vt);
    k_attn_mfma<<<BB * HEADS * NQT64 * KC, 64, 0, stream>>>(qh, kh, vt, pacc, pl);
    k_projskip<<<235, 256, 0, stream>>>(pacc, pl, wtb + WT_PROJ, proj_b, skip, pre_g, pre_b, zn);
    k_mlp1<<<235, 256, 0, stream>>>(zn, wtb + WT_W1, mlp_b1, hmid);
    k_mlp2<<<235, 256, 0, stream>>>(hmid, wtb + WT_W2, mlp_b2, zn, post_g, post_b, outp);
}

// Round 12
// 115.991 us; speedup vs baseline: 1.4814x; 1.3698x over previous
//
#include <hip/hip_runtime.h>
#include <hip/hip_bf16.h>
#include <math.h>

typedef __attribute__((ext_vector_type(8))) short bf16x8;
typedef __attribute__((ext_vector_type(4))) float f32x4;
typedef __attribute__((ext_vector_type(16))) float f32x16;
typedef unsigned short u16;
typedef unsigned int u32;

#define BB 2
#define NN 6
#define MM 625
#define HWSZ 1680
#define NQ 3750
#define NK 10080
#define HEADS 4
#define EPSV 1e-5f
#define KC 9
#define KCHUNK 1120
#define NIT 35               // KCHUNK/32 exact, no fake keys
#define NQT64 59             // ceil(3750/64)
#define QPRESCALE 0.25503489f   // (1/sqrt(32)) * log2(e)

// ---- workspace offsets (floats) ----
#define OFF_QH   0          // bf16 960000  u16 -> 480000 fl  (row-major [row][128])
#define OFF_KH   480000     // bf16 2580480 u16 -> 1290240 fl (head-major [b][h][key][32])
#define OFF_VH   1770240    // bf16 2580480 u16                (transposed [b][h][dh][key])
#define OFF_PACC 3060480    // bf16 2*4*9*3750*32 u16 -> 4320000 fl
#define OFF_PL   7380480    // 270000 fl
#define OFF_WTB  7650480    // 131072 u16 -> 65536 fl ; end 7716016

// u16 offsets inside WTB
#define WT_Q    0
#define WT_K    16384
#define WT_V    32768
#define WT_PROJ 49152
#define WT_W1   65536      // [256][128]
#define WT_W2   98304      // [128][256]

#define VEXP(d, s_) asm("v_exp_f32 %0, %1\n\ts_nop 0" : "=v"(d) : "v"(s_))
#define CVTPK(d, a, b) asm("v_cvt_pk_bf16_f32 %0, %1, %2" : "=v"(d) : "v"(a), "v"(b))

__device__ inline u16 f2bf(float f) {
    __hip_bfloat16 h = __float2bfloat16(f);
    return *reinterpret_cast<u16*>(&h);
}
__device__ inline float bf2f(u16 u) {
    u32 x = ((u32)u) << 16;
    return *reinterpret_cast<float*>(&x);
}
__device__ inline bf16x8 mk_frag(u32 a, u32 b, u32 c, u32 d) {
    union { u32 u[4]; bf16x8 v; } x;
    x.u[0] = a; x.u[1] = b; x.u[2] = c; x.u[3] = d;
    return x.v;
}

// weights -> bf16 transposed
__global__ void __launch_bounds__(256) k_prep(
        const float* __restrict__ wq, const float* __restrict__ wk,
        const float* __restrict__ wv, const float* __restrict__ pw,
        const float* __restrict__ w1, const float* __restrict__ w2,
        u16* __restrict__ wtb) {
    int idx = blockIdx.x * 256 + threadIdx.x;   // 131072 exact
    float v;
    if (idx < 65536) {
        const float* src = (idx < 16384) ? wq : (idx < 32768) ? wk
                         : (idx < 49152) ? wv : pw;
        int r = idx & 16383;
        int c = r >> 7, kk = r & 127;
        v = src[kk * 128 + c];
    } else if (idx < 98304) {
        int r = idx - 65536;
        int c = r >> 7, kk = r & 127;
        v = w1[kk * 256 + c];
    } else {
        int r = idx - 98304;
        int c = r >> 8, kk = r & 255;
        v = w2[kk * 128 + c];
    }
    wtb[idx] = f2bf(v);
}

// ONE launch for Q/K/V: LN (over 128 ch, channel-strided input) + MFMA
// 128x128 projection -> bf16. Job from blockIdx:
//   [0,235)    Q: mode 0 row-major out
//   [235,865)  K: mode 1 head-major [b][h][key][32]
//   [865,1495) V: mode 2 transposed [b][h][dh][key]
__global__ void __launch_bounds__(128) k_lnproj_all(
        const float* __restrict__ q, const float* __restrict__ k, const float* __restrict__ v,
        const float* __restrict__ gq, const float* __restrict__ bqv,
        const float* __restrict__ gk, const float* __restrict__ bkv,
        const float* __restrict__ gv, const float* __restrict__ bvv,
        const u16* __restrict__ wtb,
        const float* __restrict__ biasq, const float* __restrict__ biask,
        const float* __restrict__ biasv,
        u16* __restrict__ qh, u16* __restrict__ kh, u16* __restrict__ vt) {
    int bid = blockIdx.x;
    const float* x; const float* gam; const float* bet; const u16* wt;
    const float* bias; u16* outp;
    int S, rows, mode, g0;
    float oscale;
    if (bid < 235) {
        x = q; S = MM; rows = BB * NQ; gam = gq; bet = bqv;
        wt = wtb + WT_Q; bias = biasq; oscale = QPRESCALE; mode = 0;
        outp = qh; g0 = bid * 32;
    } else if (bid < 865) {
        x = k; S = HWSZ; rows = BB * NK; gam = gk; bet = bkv;
        wt = wtb + WT_K; bias = biask; oscale = 1.0f; mode = 1;
        outp = kh; g0 = (bid - 235) * 32;
    } else {
        x = v; S = HWSZ; rows = BB * NK; gam = gv; bet = bvv;
        wt = wtb + WT_V; bias = biasv; oscale = 1.0f; mode = 2;
        outp = vt; g0 = (bid - 865) * 32;
    }
    const int nk = NK;
    __shared__ float xs[32][132];
    __shared__ float smu[32], srs[32];
    const int t = threadIdx.x;
    {   // transposed coalesced load
        const int sl = t & 31, du = t >> 5;
        const int grow = g0 + sl;
        const bool vload = grow < rows;
        const int bn = grow / S, ss = grow % S;
        const float* xbase = x + (size_t)bn * 128 * S + ss;
        for (int it = 0; it < 32; ++it) {
            int dd = it * 4 + du;
            xs[sl][dd] = vload ? xbase[(size_t)dd * S] : 0.f;
        }
    }
    __syncthreads();
    {   // stats, 4 threads/row
        const int r = t >> 2, p = t & 3;
        float sum = 0.f, sq = 0.f;
        for (int j = 0; j < 32; ++j) {
            float vv = xs[r][p + 4 * j];
            sum += vv; sq += vv * vv;
        }
        sum += __shfl_xor(sum, 1); sq += __shfl_xor(sq, 1);
        sum += __shfl_xor(sum, 2); sq += __shfl_xor(sq, 2);
        if (p == 0) {
            float mu = sum * (1.f / 128.f);
            float var = sq * (1.f / 128.f) - mu * mu;
            smu[r] = mu;
            srs[r] = rsqrtf(var + EPSV);
        }
    }
    __syncthreads();
    {   // normalize in LDS
        const float gvv = gam[t], bvb = bet[t];
        for (int rr = 0; rr < 32; ++rr)
            xs[rr][t] = (xs[rr][t] - smu[rr]) * srs[rr] * gvv + bvb;
    }
    __syncthreads();
    // MFMA GEMM: wave wid covers cols wid*64..+63
    const int lane = t & 63, wid = t >> 6;
    const int rl = lane & 31, hi = lane >> 5;
    bf16x8 afrag[8];
    #pragma unroll
    for (int ks = 0; ks < 8; ++ks) {
        float4 u = *(const float4*)&xs[rl][ks * 16 + hi * 8];
        float4 w = *(const float4*)&xs[rl][ks * 16 + hi * 8 + 4];
        u32 d0, d1, d2, d3;
        CVTPK(d0, u.x, u.y);
        CVTPK(d1, u.z, u.w);
        CVTPK(d2, w.x, w.y);
        CVTPK(d3, w.z, w.w);
        afrag[ks] = mk_frag(d0, d1, d2, d3);
    }
    u16* au = (u16*)&xs[0][0];      // alias, used only in mode 2
    if (mode == 2) __syncthreads(); // all waves done reading xs
    #pragma unroll
    for (int tile = 0; tile < 2; ++tile) {
        const int c = wid * 64 + tile * 32 + rl;
        f32x16 acc;
        #pragma unroll
        for (int i = 0; i < 16; ++i) acc[i] = 0.f;
        #pragma unroll
        for (int ks = 0; ks < 8; ++ks) {
            bf16x8 bfrag = *(const bf16x8*)(wt + (size_t)c * 128 + ks * 16 + hi * 8);
            acc = __builtin_amdgcn_mfma_f32_32x32x16_bf16(afrag[ks], bfrag, acc, 0, 0, 0);
        }
        const float bb = bias[c];
        #pragma unroll
        for (int reg = 0; reg < 16; ++reg) {
            int row = (reg & 3) + 8 * (reg >> 2) + 4 * hi;
            int grow = g0 + row;
            u16 val = f2bf((acc[reg] + bb) * oscale);
            if (mode == 2) {
                au[row * 132 + c] = val;
            } else if (mode == 1) {
                if (grow < rows) {
                    int b = (grow >= nk) ? 1 : 0;
                    int key = grow - b * nk;
                    outp[(((size_t)b * HEADS + (c >> 5)) * nk + key) * 32 + (c & 31)] = val;
                }
            } else {
                if (grow < rows) outp[(size_t)grow * 128 + c] = val;
            }
        }
    }
    if (mode == 2) {
        __syncthreads();
        const int b = (g0 >= nk) ? 1 : 0;
        const int key0 = g0 - b * nk;
        for (int it = 0; it < 32; ++it) {
            int idx = it * 128 + t;
            int chan = idx >> 5, key = idx & 31;
            outp[(((size_t)b * HEADS + (chan >> 5)) * 32 + (chan & 31)) * (size_t)nk + key0 + key]
                = au[key * 132 + chan];
        }
    }
}

// MFMA flash attention partial (R8 structure, proven): 1 wave/block, 64 q/wave
// (2 q-tiles), NO LDS, NO barriers, 1-2 iter register prefetch.
__global__ void __launch_bounds__(64, 3) k_attn_mfma(
        const u16* __restrict__ qh, const u16* __restrict__ kh, const u16* __restrict__ vt,
        u16* __restrict__ pacc, float* __restrict__ pl) {
    const int lane = threadIdx.x;
    const int rl = lane & 31, hi = lane >> 5;
    const int bid = blockIdx.x;
    // XCD swizzle: 4248 = 8 x 531; each XCD owns exactly one bh
    const int wg = (bid & 7) * 531 + (bid >> 3);
    const int qt = wg % NQT64;
    const int rest = wg / NQT64;
    const int kc = rest % KC;
    const int bh = rest / KC;
    const int b = bh >> 2, h = bh & 3;
    const int q0A = qt * 64, q0B = q0A + 32;

    int qrowA = q0A + rl; if (qrowA > NQ - 1) qrowA = NQ - 1;
    int qrowB = q0B + rl; if (qrowB > NQ - 1) qrowB = NQ - 1;
    const u16* qpA = qh + ((size_t)b * NQ + qrowA) * 128 + h * 32;
    const u16* qpB = qh + ((size_t)b * NQ + qrowB) * 128 + h * 32;
    const bf16x8 qfA0 = *(const bf16x8*)(qpA + hi * 8);
    const bf16x8 qfA1 = *(const bf16x8*)(qpA + 16 + hi * 8);
    const bf16x8 qfB0 = *(const bf16x8*)(qpB + hi * 8);
    const bf16x8 qfB1 = *(const bf16x8*)(qpB + 16 + hi * 8);

    const int kstart = kc * KCHUNK;
    const u16* kptr = kh + ((size_t)bh * NK + kstart) * 32 + rl * 32 + hi * 8;
    const u16* vptr = vt + ((size_t)(bh * 32 + rl)) * NK + kstart + hi * 8;

    f32x16 accA, accB, zero16;
    #pragma unroll
    for (int i = 0; i < 16; ++i) { accA[i] = 0.f; accB[i] = 0.f; zero16[i] = 0.f; }
    f32x4 lsA = {0.f, 0.f, 0.f, 0.f}, lsB = {0.f, 0.f, 0.f, 0.f};

    bf16x8 k0a = *(const bf16x8*)(kptr);
    bf16x8 k0b = *(const bf16x8*)(kptr + 16);
    bf16x8 v0a = *(const bf16x8*)(vptr);
    bf16x8 v0b = *(const bf16x8*)(vptr + 16);
    bf16x8 k1a = *(const bf16x8*)(kptr + 1024);
    bf16x8 k1b = *(const bf16x8*)(kptr + 1024 + 16);
    bf16x8 v1a = *(const bf16x8*)(vptr + 32);
    bf16x8 v1b = *(const bf16x8*)(vptr + 32 + 16);

#define ATT_BODY(II, KA, KB, VA, VB)                                              \
    {                                                                             \
        __builtin_amdgcn_s_setprio(1);                                            \
        f32x16 sA = __builtin_amdgcn_mfma_f32_32x32x16_bf16(KA, qfA0, zero16, 0, 0, 0); \
        sA = __builtin_amdgcn_mfma_f32_32x32x16_bf16(KB, qfA1, sA, 0, 0, 0);      \
        f32x16 sB = __builtin_amdgcn_mfma_f32_32x32x16_bf16(KA, qfB0, zero16, 0, 0, 0); \
        sB = __builtin_amdgcn_mfma_f32_32x32x16_bf16(KB, qfB1, sB, 0, 0, 0);      \
        __builtin_amdgcn_s_setprio(0);                                            \
        int nid = ((II) + 2 < NIT) ? (II) + 2 : 0;                                \
        KA = *(const bf16x8*)(kptr + (size_t)nid * 1024);                         \
        KB = *(const bf16x8*)(kptr + (size_t)nid * 1024 + 16);                    \
        u32 a0, a1, a2, a3, a4, a5, a6, a7;                                       \
        u32 b0, b1, b2, b3, b4, b5, b6, b7;                                       \
        {                                                                         \
            float e0, e1, e2, e3;                                                 \
            VEXP(e0, sA[0]);  VEXP(e1, sA[1]);  VEXP(e2, sA[2]);  VEXP(e3, sA[3]);\
            CVTPK(a0, e0, e1); CVTPK(a1, e2, e3);                                 \
            lsA += (f32x4){e0, e1, e2, e3};                                       \
            VEXP(e0, sA[4]);  VEXP(e1, sA[5]);  VEXP(e2, sA[6]);  VEXP(e3, sA[7]);\
            CVTPK(a2, e0, e1); CVTPK(a3, e2, e3);                                 \
            lsA += (f32x4){e0, e1, e2, e3};                                       \
            VEXP(e0, sA[8]);  VEXP(e1, sA[9]);  VEXP(e2, sA[10]); VEXP(e3, sA[11]);\
            CVTPK(a4, e0, e1); CVTPK(a5, e2, e3);                                 \
            lsA += (f32x4){e0, e1, e2, e3};                                       \
            VEXP(e0, sA[12]); VEXP(e1, sA[13]); VEXP(e2, sA[14]); VEXP(e3, sA[15]);\
            CVTPK(a6, e0, e1); CVTPK(a7, e2, e3);                                 \
            lsA += (f32x4){e0, e1, e2, e3};                                       \
            VEXP(e0, sB[0]);  VEXP(e1, sB[1]);  VEXP(e2, sB[2]);  VEXP(e3, sB[3]);\
            CVTPK(b0, e0, e1); CVTPK(b1, e2, e3);                                 \
            lsB += (f32x4){e0, e1, e2, e3};                                       \
            VEXP(e0, sB[4]);  VEXP(e1, sB[5]);  VEXP(e2, sB[6]);  VEXP(e3, sB[7]);\
            CVTPK(b2, e0, e1); CVTPK(b3, e2, e3);                                 \
            lsB += (f32x4){e0, e1, e2, e3};                                       \
            VEXP(e0, sB[8]);  VEXP(e1, sB[9]);  VEXP(e2, sB[10]); VEXP(e3, sB[11]);\
            CVTPK(b4, e0, e1); CVTPK(b5, e2, e3);                                 \
            lsB += (f32x4){e0, e1, e2, e3};                                       \
            VEXP(e0, sB[12]); VEXP(e1, sB[13]); VEXP(e2, sB[14]); VEXP(e3, sB[15]);\
            CVTPK(b6, e0, e1); CVTPK(b7, e2, e3);                                 \
            lsB += (f32x4){e0, e1, e2, e3};                                       \
        }                                                                         \
        asm("v_permlane32_swap_b32 %0, %1" : "+v"(a0), "+v"(a2));                 \
        asm("v_permlane32_swap_b32 %0, %1" : "+v"(a1), "+v"(a3));                 \
        asm("v_permlane32_swap_b32 %0, %1" : "+v"(a4), "+v"(a6));                 \
        asm("v_permlane32_swap_b32 %0, %1" : "+v"(a5), "+v"(a7));                 \
        asm("v_permlane32_swap_b32 %0, %1" : "+v"(b0), "+v"(b2));                 \
        asm("v_permlane32_swap_b32 %0, %1" : "+v"(b1), "+v"(b3));                 \
        asm("v_permlane32_swap_b32 %0, %1" : "+v"(b4), "+v"(b6));                 \
        asm("v_permlane32_swap_b32 %0, %1" : "+v"(b5), "+v"(b7));                 \
        const bf16x8 pA0 = mk_frag(a0, a1, a2, a3);                               \
        const bf16x8 pA1 = mk_frag(a4, a5, a6, a7);                               \
        const bf16x8 pB0 = mk_frag(b0, b1, b2, b3);                               \
        const bf16x8 pB1 = mk_frag(b4, b5, b6, b7);                               \
        __builtin_amdgcn_s_setprio(1);                                            \
        accA = __builtin_amdgcn_mfma_f32_32x32x16_bf16(pA0, VA, accA, 0, 0, 0);   \
        accA = __builtin_amdgcn_mfma_f32_32x32x16_bf16(pA1, VB, accA, 0, 0, 0);   \
        accB = __builtin_amdgcn_mfma_f32_32x32x16_bf16(pB0, VA, accB, 0, 0, 0);   \
        accB = __builtin_amdgcn_mfma_f32_32x32x16_bf16(pB1, VB, accB, 0, 0, 0);   \
        __builtin_amdgcn_s_setprio(0);                                            \
        VA = *(const bf16x8*)(vptr + (size_t)nid * 32);                           \
        VB = *(const bf16x8*)(vptr + (size_t)nid * 32 + 16);                      \
    }

    for (int ii = 0; ii + 1 < NIT; ii += 2) {
        ATT_BODY(ii, k0a, k0b, v0a, v0b);
        ATT_BODY(ii + 1, k1a, k1b, v1a, v1b);
    }
    ATT_BODY(NIT - 1, k0a, k0b, v0a, v0b);   // NIT odd: last iter uses stage 0
#undef ATT_BODY

    float lsumA = (lsA[0] + lsA[1]) + (lsA[2] + lsA[3]);
    float lsumB = (lsB[0] + lsB[1]) + (lsB[2] + lsB[3]);
    float ltotA = lsumA + __shfl_xor(lsumA, 32);
    float ltotB = lsumB + __shfl_xor(lsumB, 32);

    const int pi = bh * KC + kc;
    #pragma unroll
    for (int reg = 0; reg < 16; ++reg) {
        int qloc = (reg & 3) + 8 * (reg >> 2) + 4 * hi;
        int qqA = q0A + qloc;
        int qqB = q0B + qloc;
        if (qqA < NQ) pacc[((size_t)pi * NQ + qqA) * 32 + rl] = f2bf(accA[reg]);
        if (qqB < NQ) pacc[((size_t)pi * NQ + qqB) * 32 + rl] = f2bf(accB[reg]);
    }
    if (hi == 0) {
        int qqA = q0A + rl, qqB = q0B + rl;
        if (qqA < NQ) pl[(size_t)pi * NQ + qqA] = ltotA;
        if (qqB < NQ) pl[(size_t)pi * NQ + qqB] = ltotB;
    }
}

// fully fused tail: combine -> proj -> +skip -> pre-LN -> mlp1(gelu) -> mlp2
// -> +residual -> post-LN -> transposed fp32 store. All intermediates in LDS.
__global__ void __launch_bounds__(256) k_tail(
        const u16* __restrict__ pacc, const float* __restrict__ pl,
        const u16* __restrict__ wproj, const float* __restrict__ bproj,
        const float* __restrict__ skip,
        const float* __restrict__ pre_g, const float* __restrict__ pre_b,
        const u16* __restrict__ w1, const float* __restrict__ b1,
        const u16* __restrict__ w2, const float* __restrict__ b2,
        const float* __restrict__ post_g, const float* __restrict__ post_b,
        float* __restrict__ outp) {
    __shared__ u16 au[32 * 136];       // combine out; later reused as zn bf16
    __shared__ float zs[32][132];      // z (proj+skip); later z2 (mlp2 out + res)
    __shared__ u16 hs[32 * 264];       // gelu hidden, bf16
    __shared__ float rLs[32][4];
    __shared__ float smu[32], srs[32];
    const int t = threadIdx.x;
    const int g0 = blockIdx.x * 32;
    const int rows = BB * NQ;
    const int lane = t & 63, wid = t >> 6;
    const int rl = lane & 31, hi = lane >> 5;

    if (t < 128) {   // reciprocal denominators
        int row = t >> 2, h = t & 3;
        int grow = g0 + row;
        float L = 1.f;
        if (grow < rows) {
            int b = grow / NQ, qq = grow - b * NQ;
            L = 0.f;
            #pragma unroll
            for (int kc = 0; kc < KC; ++kc)
                L += pl[(size_t)((b * HEADS + h) * KC + kc) * NQ + qq];
        }
        rLs[row][h] = 1.f / L;
    }
    __syncthreads();
    #pragma unroll
    for (int it = 0; it < 16; ++it) {   // combine partials into a-tile
        int idx = it * 256 + t;
        int row = idx >> 7, col = idx & 127;
        int grow = g0 + row;
        u16 outv = 0;
        if (grow < rows) {
            int b = grow / NQ, qq = grow - b * NQ;
            int h = col >> 5, j = col & 31;
            float val = 0.f;
            #pragma unroll
            for (int kc = 0; kc < KC; ++kc)
                val += bf2f(pacc[((size_t)((b * HEADS + h) * KC + kc) * NQ + qq) * 32 + j]);
            outv = f2bf(val * rLs[row][h]);
        }
        au[row * 136 + col] = outv;
    }
    __syncthreads();
    {   // proj MFMA: c = wid*32+rl
        const int c = wid * 32 + rl;
        f32x16 acc;
        #pragma unroll
        for (int i = 0; i < 16; ++i) acc[i] = 0.f;
        #pragma unroll
        for (int ks = 0; ks < 8; ++ks) {
            bf16x8 af = *(const bf16x8*)&au[rl * 136 + ks * 16 + hi * 8];
            bf16x8 bf = *(const bf16x8*)(wproj + (size_t)c * 128 + ks * 16 + hi * 8);
            acc = __builtin_amdgcn_mfma_f32_32x32x16_bf16(af, bf, acc, 0, 0, 0);
        }
        const float bb = bproj[c];
        #pragma unroll
        for (int reg = 0; reg < 16; ++reg) {
            int row = (reg & 3) + 8 * (reg >> 2) + 4 * hi;
            zs[row][c] = acc[reg] + bb;
        }
    }
    __syncthreads();
    {   // skip add (channel-strided)
        const int sl = t & 31, du = t >> 5;   // du 0..7
        const int grow = g0 + sl;
        if (grow < rows) {
            const int bn = grow / MM, mm = grow % MM;
            const float* sbase = skip + (size_t)bn * 128 * MM + mm;
            for (int it = 0; it < 16; ++it) {
                int dd = it * 8 + du;
                zs[sl][dd] += sbase[(size_t)dd * MM];
            }
        }
    }
    __syncthreads();
    {   // pre-LN stats, 8 threads/row
        const int r = t >> 3, p = t & 7;
        float sum = 0.f, sq = 0.f;
        for (int j = 0; j < 16; ++j) {
            float v = zs[r][p + 8 * j];
            sum += v; sq += v * v;
        }
        sum += __shfl_xor(sum, 1); sq += __shfl_xor(sq, 1);
        sum += __shfl_xor(sum, 2); sq += __shfl_xor(sq, 2);
        sum += __shfl_xor(sum, 4); sq += __shfl_xor(sq, 4);
        if (p == 0) {
            float mu = sum * (1.f / 128.f);
            float var = sq * (1.f / 128.f) - mu * mu;
            smu[r] = mu; srs[r] = rsqrtf(var + EPSV);
        }
    }
    __syncthreads();
    {   // normalize -> zn (bf16) into au space
        const int cc = t & 127, rh = t >> 7;
        const float gv = pre_g[cc], bv = pre_b[cc];
        for (int i = 0; i < 16; ++i) {
            int rr = rh * 16 + i;
            au[rr * 136 + cc] = f2bf((zs[rr][cc] - smu[rr]) * srs[rr] * gv + bv);
        }
    }
    __syncthreads();
    {   // mlp1: 2 col-tiles/wave, gelu, -> hs
        bf16x8 afrag[8];
        #pragma unroll
        for (int ks = 0; ks < 8; ++ks)
            afrag[ks] = *(const bf16x8*)&au[rl * 136 + ks * 16 + hi * 8];
        #pragma unroll
        for (int tile = 0; tile < 2; ++tile) {
            const int c = wid * 64 + tile * 32 + rl;
            f32x16 acc;
            #pragma unroll
            for (int i = 0; i < 16; ++i) acc[i] = 0.f;
            #pragma unroll
            for (int ks = 0; ks < 8; ++ks) {
                bf16x8 bf = *(const bf16x8*)(w1 + (size_t)c * 128 + ks * 16 + hi * 8);
                acc = __builtin_amdgcn_mfma_f32_32x32x16_bf16(afrag[ks], bf, acc, 0, 0, 0);
            }
            const float bb = b1[c];
            #pragma unroll
            for (int reg = 0; reg < 16; ++reg) {
                int row = (reg & 3) + 8 * (reg >> 2) + 4 * hi;
                float x = acc[reg] + bb;
                float gl = 0.5f * x * (1.f + erff(x * 0.70710678118654752f));
                hs[row * 264 + c] = f2bf(gl);
            }
        }
    }
    __syncthreads();
    {   // mlp2 + residual -> zs
        const int c = wid * 32 + rl;
        f32x16 acc;
        #pragma unroll
        for (int i = 0; i < 16; ++i) acc[i] = 0.f;
        #pragma unroll
        for (int ks = 0; ks < 16; ++ks) {
            bf16x8 af = *(const bf16x8*)&hs[rl * 264 + ks * 16 + hi * 8];
            bf16x8 bf = *(const bf16x8*)(w2 + (size_t)c * 256 + ks * 16 + hi * 8);
            acc = __builtin_amdgcn_mfma_f32_32x32x16_bf16(af, bf, acc, 0, 0, 0);
        }
        const float bb = b2[c];
        #pragma unroll
        for (int reg = 0; reg < 16; ++reg) {
            int row = (reg & 3) + 8 * (reg >> 2) + 4 * hi;
            zs[row][c] = acc[reg] + bb + bf2f(au[row * 136 + c]);
        }
    }
    __syncthreads();
    {   // post-LN stats
        const int r = t >> 3, p = t & 7;
        float sum = 0.f, sq = 0.f;
        for (int j = 0; j < 16; ++j) {
            float v = zs[r][p + 8 * j];
            sum += v; sq += v * v;
        }
        sum += __shfl_xor(sum, 1); sq += __shfl_xor(sq, 1);
        sum += __shfl_xor(sum, 2); sq += __shfl_xor(sq, 2);
        sum += __shfl_xor(sum, 4); sq += __shfl_xor(sq, 4);
        if (p == 0) {
            float mu = sum * (1.f / 128.f);
            float var = sq * (1.f / 128.f) - mu * mu;
            smu[r] = mu; srs[r] = rsqrtf(var + EPSV);
        }
    }
    __syncthreads();
    {   // transposed store
        const int sl = t & 31, du = t >> 5;   // du 0..7
        const int grow = g0 + sl;
        if (grow < rows) {
            const int bn = grow / MM, mm = grow % MM;
            const float mu = smu[sl], rs = srs[sl];
            float* obase = outp + (size_t)bn * 128 * MM + mm;
            for (int it = 0; it < 16; ++it) {
                int dd = it * 8 + du;
                obase[(size_t)dd * MM] = (zs[sl][dd] - mu) * rs * post_g[dd] + post_b[dd];
            }
        }
    }
}

extern "C" void kernel_launch(void* const* d_in, const int* in_sizes, int n_in,
                              void* d_out, int out_size, void* d_ws, size_t ws_size,
                              hipStream_t stream) {
    const float* q      = (const float*)d_in[0];
    const float* k      = (const float*)d_in[1];
    const float* v      = (const float*)d_in[2];
    const float* skip   = (const float*)d_in[3];
    const float* ln_q_g = (const float*)d_in[4];
    const float* ln_q_b = (const float*)d_in[5];
    const float* wq     = (const float*)d_in[6];
    const float* bq     = (const float*)d_in[7];
    const float* ln_k_g = (const float*)d_in[8];
    const float* ln_k_b = (const float*)d_in[9];
    const float* wk     = (const float*)d_in[10];
    const float* bk     = (const float*)d_in[11];
    const float* ln_v_g = (const float*)d_in[12];
    const float* ln_v_b = (const float*)d_in[13];
    const float* wv     = (const float*)d_in[14];
    const float* bv     = (const float*)d_in[15];
    const float* proj_w = (const float*)d_in[16];
    const float* proj_b = (const float*)d_in[17];
    const float* pre_g  = (const float*)d_in[18];
    const float* pre_b  = (const float*)d_in[19];
    const float* mlp_w1 = (const float*)d_in[20];
    const float* mlp_b1 = (const float*)d_in[21];
    const float* mlp_w2 = (const float*)d_in[22];
    const float* mlp_b2 = (const float*)d_in[23];
    const float* post_g = (const float*)d_in[24];
    const float* post_b = (const float*)d_in[25];

    float* ws   = (float*)d_ws;
    float* outp = (float*)d_out;

    u16* qh   = (u16*)(ws + OFF_QH);
    u16* kh   = (u16*)(ws + OFF_KH);
    u16* vt   = (u16*)(ws + OFF_VH);
    u16* pacc = (u16*)(ws + OFF_PACC);
    float* pl   = ws + OFF_PL;
    u16* wtb  = (u16*)(ws + OFF_WTB);

    k_prep<<<512, 256, 0, stream>>>(wq, wk, wv, proj_w, mlp_w1, mlp_w2, wtb);
    k_lnproj_all<<<1495, 128, 0, stream>>>(q, k, v,
        ln_q_g, ln_q_b, ln_k_g, ln_k_b, ln_v_g, ln_v_b,
        wtb, bq, bk, bv, qh, kh, vt);
    k_attn_mfma<<<BB * HEADS * NQT64 * KC, 64, 0, stream>>>(qh, kh, vt, pacc, pl);
    k_tail<<<235, 256, 0, stream>>>(pacc, pl, wtb + WT_PROJ, proj_b, skip,
        pre_g, pre_b, wtb + WT_W1, mlp_b1, wtb + WT_W2, mlp_b2,
        post_g, post_b, outp);
}